// Round 1
// baseline (395.276 us; speedup 1.0000x reference)
//
#include <hip/hip_runtime.h>
#include <hip/hip_bf16.h>

#define FEAT    256
#define KDIM    512   // FEAT + EMBED
#define EMBED   256
#define BATCH   50000
#define NSAMP   25
#define NAN_FILL 0.01f

typedef __attribute__((ext_vector_type(8))) short short8;
typedef __attribute__((ext_vector_type(4))) float floatx4;

// ---------------- Stage 1: gather + mean -> combined [BATCH, 512] bf16 ----------------
__global__ __launch_bounds__(256) void agg_kernel(
    const float* __restrict__ features,
    const int*   __restrict__ nodes,
    const int*   __restrict__ neigh,     // [BATCH, NSAMP]
    __hip_bfloat16* __restrict__ comb)   // [BATCH, KDIM]
{
    const int b = blockIdx.x;
    const int f = threadIdx.x;           // 0..255

    const int node = nodes[b];
    const float self = features[(size_t)node * FEAT + f];

    const int* nb = neigh + (size_t)b * NSAMP;
    float sum = 0.f;
    #pragma unroll
    for (int j = 0; j < NSAMP; ++j) {
        const int idx = nb[j];
        sum += features[(size_t)idx * FEAT + f];
    }
    float m = sum * (1.0f / NSAMP);
    if (m != m) m = NAN_FILL;            // isnan -> fill (matches reference)

    __hip_bfloat16* row = comb + (size_t)b * KDIM;
    row[f]        = __float2bfloat16(self);
    row[FEAT + f] = __float2bfloat16(m);
}

// ---------------- Stage 1b: W f32 -> bf16 ----------------
__global__ __launch_bounds__(256) void wconv_kernel(
    const float* __restrict__ W, __hip_bfloat16* __restrict__ Wb)
{
    const int i = blockIdx.x * 256 + threadIdx.x;   // grid sized exactly 256*512
    Wb[i] = __float2bfloat16(W[i]);
}

// ---------------- Stage 2: out[e,b] = relu(sum_k W[e,k] * C[b,k]) ----------------
// M = 256 (all of E, 4 waves x 64 rows), N-tile = 64 columns/block, K = 512.
// MFMA 16x16x32 bf16. Fragment layouts (guide-verified on gfx950):
//   A: lane holds A[m = lane&15][k = (lane>>4)*8 + j], j=0..7  (16B contiguous)
//   B: lane holds B[k = (lane>>4)*8 + j][n = lane&15]
//   D: lane,reg -> row = (lane>>4)*4 + reg, col = lane&15
__global__ __launch_bounds__(256) void gemm_kernel(
    const __hip_bfloat16* __restrict__ Wb,   // [256, 512] row-major
    const __hip_bfloat16* __restrict__ Cb,   // [BATCH, 512] row-major
    float* __restrict__ out)                 // [256, BATCH] row-major
{
    const int lane  = threadIdx.x & 63;
    const int wave  = threadIdx.x >> 6;
    const int q     = lane >> 4;       // quad 0..3
    const int r     = lane & 15;
    const int mbase = wave * 64;       // wave covers rows [mbase, mbase+64)
    const int nbase = blockIdx.x * 64; // block covers cols [nbase, nbase+64)

    // clamp column indices for the ragged last block (stores are guarded)
    int ncol[4];
    #pragma unroll
    for (int nt = 0; nt < 4; ++nt) {
        int c = nbase + nt * 16 + r;
        ncol[nt] = c < BATCH ? c : (BATCH - 1);
    }

    const short* Wp = (const short*)Wb;
    const short* Cp = (const short*)Cb;

    floatx4 acc[4][4] = {};

    for (int k = 0; k < KDIM; k += 32) {
        short8 afr[4], bfr[4];
        #pragma unroll
        for (int mt = 0; mt < 4; ++mt) {
            const short* p = Wp + (size_t)(mbase + mt * 16 + r) * KDIM + k + q * 8;
            afr[mt] = *(const short8*)p;
        }
        #pragma unroll
        for (int nt = 0; nt < 4; ++nt) {
            const short* p = Cp + (size_t)ncol[nt] * KDIM + k + q * 8;
            bfr[nt] = *(const short8*)p;
        }
        #pragma unroll
        for (int mt = 0; mt < 4; ++mt)
            #pragma unroll
            for (int nt = 0; nt < 4; ++nt)
                acc[mt][nt] = __builtin_amdgcn_mfma_f32_16x16x32_bf16(
                    afr[mt], bfr[nt], acc[mt][nt], 0, 0, 0);
    }

    // epilogue: ReLU + store
    #pragma unroll
    for (int mt = 0; mt < 4; ++mt) {
        #pragma unroll
        for (int nt = 0; nt < 4; ++nt) {
            const int col = nbase + nt * 16 + r;
            if (col < BATCH) {
                #pragma unroll
                for (int i = 0; i < 4; ++i) {
                    const int row = mbase + mt * 16 + q * 4 + i;
                    float v = acc[mt][nt][i];
                    out[(size_t)row * BATCH + col] = v > 0.f ? v : 0.f;
                }
            }
        }
    }
}

extern "C" void kernel_launch(void* const* d_in, const int* in_sizes, int n_in,
                              void* d_out, int out_size, void* d_ws, size_t ws_size,
                              hipStream_t stream) {
    const float* features = (const float*)d_in[0];   // [100000, 256] f32
    const float* weight   = (const float*)d_in[1];   // [256, 512] f32
    const int*   nodes    = (const int*)d_in[2];     // [50000]
    const int*   neigh    = (const int*)d_in[3];     // [50000, 25]
    float* out = (float*)d_out;                      // [256, 50000] f32

    __hip_bfloat16* comb = (__hip_bfloat16*)d_ws;                  // 50000*512*2 = 51.2 MB
    __hip_bfloat16* Wb   = comb + (size_t)BATCH * KDIM;            // +256 KB

    agg_kernel<<<BATCH, 256, 0, stream>>>(features, nodes, neigh, comb);
    wconv_kernel<<<(256 * KDIM) / 256, 256, 0, stream>>>(weight, Wb);

    const int nblocks = (BATCH + 63) / 64;  // 782
    gemm_kernel<<<nblocks, 256, 0, stream>>>(Wb, comb, out);
}

// Round 2
// 325.143 us; speedup vs baseline: 1.2157x; 1.2157x over previous
//
#include <hip/hip_runtime.h>
#include <hip/hip_bf16.h>

#define FEAT    256
#define KDIM    512   // FEAT + EMBED
#define EMBED   256
#define BATCH   50000
#define NSAMP   25
#define N_NODES 100000
#define NAN_FILL 0.01f

typedef __attribute__((ext_vector_type(8))) short  short8;
typedef __attribute__((ext_vector_type(4))) float  floatx4;
typedef __attribute__((ext_vector_type(4))) unsigned short ushort4v;
typedef __attribute__((ext_vector_type(8))) unsigned short ushort8v;
typedef __attribute__((ext_vector_type(4))) float  float4v;

__device__ inline unsigned short f2bf(float x) {
    __hip_bfloat16 h = __float2bfloat16(x);
    union { __hip_bfloat16 h; unsigned short u; } c; c.h = h;
    return c.u;
}
__device__ inline float bf2f(unsigned short u) {
    union { unsigned int i; float f; } c; c.i = ((unsigned int)u) << 16;
    return c.f;
}

// ---------------- Stage 0: features f32 -> bf16 table ----------------
// 25.6M elements; each thread converts 8 (two float4 loads, one 16B store).
__global__ __launch_bounds__(256) void fconv_kernel(
    const float* __restrict__ F, unsigned short* __restrict__ Fb)
{
    const size_t i = ((size_t)blockIdx.x * 256 + threadIdx.x) * 8;
    float4v a = *(const float4v*)(F + i);
    float4v b = *(const float4v*)(F + i + 4);
    ushort8v o;
    o[0] = f2bf(a[0]); o[1] = f2bf(a[1]); o[2] = f2bf(a[2]); o[3] = f2bf(a[3]);
    o[4] = f2bf(b[0]); o[5] = f2bf(b[1]); o[6] = f2bf(b[2]); o[7] = f2bf(b[3]);
    *(ushort8v*)(Fb + i) = o;
}

// ---------------- Stage 1: gather + mean -> combined [BATCH, 512] bf16 ----------------
// One WAVE per batch item; lane covers 4 consecutive features (8B loads, 512B/row/wave).
__global__ __launch_bounds__(256) void agg_kernel(
    const unsigned short* __restrict__ Fb,   // [N_NODES, 256] bf16
    const int*   __restrict__ nodes,
    const int*   __restrict__ neigh,         // [BATCH, NSAMP]
    unsigned short* __restrict__ comb)       // [BATCH, 512] bf16
{
    const int wave = threadIdx.x >> 6;
    const int lane = threadIdx.x & 63;
    const int b = blockIdx.x * 4 + wave;     // 12500 blocks * 4 = 50000 exactly

    const int node = nodes[b];
    const ushort4v selfv = *(const ushort4v*)(Fb + (size_t)node * FEAT + lane * 4);

    const int* nb = neigh + (size_t)b * NSAMP;
    float s0 = 0.f, s1 = 0.f, s2 = 0.f, s3 = 0.f;
    #pragma unroll
    for (int j = 0; j < NSAMP; ++j) {
        const int idx = nb[j];               // wave-uniform -> scalar load
        ushort4v t = *(const ushort4v*)(Fb + (size_t)idx * FEAT + lane * 4);
        s0 += bf2f(t[0]); s1 += bf2f(t[1]); s2 += bf2f(t[2]); s3 += bf2f(t[3]);
    }
    const float inv = 1.0f / NSAMP;
    float m0 = s0 * inv, m1 = s1 * inv, m2 = s2 * inv, m3 = s3 * inv;
    if (m0 != m0) m0 = NAN_FILL;
    if (m1 != m1) m1 = NAN_FILL;
    if (m2 != m2) m2 = NAN_FILL;
    if (m3 != m3) m3 = NAN_FILL;

    unsigned short* row = comb + (size_t)b * KDIM;
    *(ushort4v*)(row + lane * 4) = selfv;
    ushort4v mv; mv[0] = f2bf(m0); mv[1] = f2bf(m1); mv[2] = f2bf(m2); mv[3] = f2bf(m3);
    *(ushort4v*)(row + FEAT + lane * 4) = mv;
}

// ---------------- Stage 1b: W f32 -> bf16 ----------------
__global__ __launch_bounds__(256) void wconv_kernel(
    const float* __restrict__ W, unsigned short* __restrict__ Wb)
{
    const int i = blockIdx.x * 256 + threadIdx.x;   // grid sized exactly 256*512
    Wb[i] = f2bf(W[i]);
}

// ---------------- Stage 2: out[e,b] = relu(sum_k W[e,k] * C[b,k]) ----------------
// M = 256 (all of E, 4 waves x 64 rows), N-tile = 64 columns/block, K = 512.
// MFMA 16x16x32 bf16. Fragment layouts (guide-verified on gfx950):
//   A: lane holds A[m = lane&15][k = (lane>>4)*8 + j], j=0..7  (16B contiguous)
//   B: lane holds B[k = (lane>>4)*8 + j][n = lane&15]
//   D: lane,reg -> row = (lane>>4)*4 + reg, col = lane&15
__global__ __launch_bounds__(256) void gemm_kernel(
    const unsigned short* __restrict__ Wb,   // [256, 512] bf16 row-major
    const unsigned short* __restrict__ Cb,   // [BATCH, 512] bf16 row-major
    float* __restrict__ out)                 // [256, BATCH] f32 row-major
{
    const int lane  = threadIdx.x & 63;
    const int wave  = threadIdx.x >> 6;
    const int q     = lane >> 4;       // quad 0..3
    const int r     = lane & 15;
    const int mbase = wave * 64;       // wave covers rows [mbase, mbase+64)
    const int nbase = blockIdx.x * 64; // block covers cols [nbase, nbase+64)

    int ncol[4];
    #pragma unroll
    for (int nt = 0; nt < 4; ++nt) {
        int c = nbase + nt * 16 + r;
        ncol[nt] = c < BATCH ? c : (BATCH - 1);
    }

    const short* Wp = (const short*)Wb;
    const short* Cp = (const short*)Cb;

    floatx4 acc[4][4] = {};

    for (int k = 0; k < KDIM; k += 32) {
        short8 afr[4], bfr[4];
        #pragma unroll
        for (int mt = 0; mt < 4; ++mt) {
            const short* p = Wp + (size_t)(mbase + mt * 16 + r) * KDIM + k + q * 8;
            afr[mt] = *(const short8*)p;
        }
        #pragma unroll
        for (int nt = 0; nt < 4; ++nt) {
            const short* p = Cp + (size_t)ncol[nt] * KDIM + k + q * 8;
            bfr[nt] = *(const short8*)p;
        }
        #pragma unroll
        for (int mt = 0; mt < 4; ++mt)
            #pragma unroll
            for (int nt = 0; nt < 4; ++nt)
                acc[mt][nt] = __builtin_amdgcn_mfma_f32_16x16x32_bf16(
                    afr[mt], bfr[nt], acc[mt][nt], 0, 0, 0);
    }

    #pragma unroll
    for (int mt = 0; mt < 4; ++mt) {
        #pragma unroll
        for (int nt = 0; nt < 4; ++nt) {
            const int col = nbase + nt * 16 + r;
            if (col < BATCH) {
                #pragma unroll
                for (int i = 0; i < 4; ++i) {
                    const int row = mbase + mt * 16 + q * 4 + i;
                    float v = acc[mt][nt][i];
                    out[(size_t)row * BATCH + col] = v > 0.f ? v : 0.f;
                }
            }
        }
    }
}

extern "C" void kernel_launch(void* const* d_in, const int* in_sizes, int n_in,
                              void* d_out, int out_size, void* d_ws, size_t ws_size,
                              hipStream_t stream) {
    const float* features = (const float*)d_in[0];   // [100000, 256] f32
    const float* weight   = (const float*)d_in[1];   // [256, 512] f32
    const int*   nodes    = (const int*)d_in[2];     // [50000]
    const int*   neigh    = (const int*)d_in[3];     // [50000, 25]
    float* out = (float*)d_out;                      // [256, 50000] f32

    unsigned short* comb = (unsigned short*)d_ws;                    // 51.2 MB
    unsigned short* Wb   = comb + (size_t)BATCH * KDIM;              // +0.25 MB
    unsigned short* Fb   = Wb + (size_t)EMBED * KDIM;                // +51.2 MB

    // features -> bf16 table (25.6M elems / (256 thr * 8) = 12500 blocks)
    fconv_kernel<<<(N_NODES * FEAT) / (256 * 8), 256, 0, stream>>>(features, Fb);
    wconv_kernel<<<(EMBED * KDIM) / 256, 256, 0, stream>>>(weight, Wb);
    agg_kernel<<<BATCH / 4, 256, 0, stream>>>(Fb, nodes, neigh, comb);

    const int nblocks = (BATCH + 63) / 64;  // 782
    gemm_kernel<<<nblocks, 256, 0, stream>>>(Wb, comb, out);
}

// Round 3
// 256.871 us; speedup vs baseline: 1.5388x; 1.2658x over previous
//
#include <hip/hip_runtime.h>
#include <hip/hip_bf16.h>
#include <hip/hip_fp8.h>

#define FEAT    256
#define KDIM    512   // FEAT + EMBED
#define EMBED   256
#define BATCH   50000
#define NSAMP   25
#define N_NODES 100000
#define NAN_FILL 0.01f

#define NTILE   48    // batch items per block (LDS tile rows)
#define LSTRIDE 520   // shorts per LDS row: 512 + 8 pad -> 260 words == 4 (mod 32)
                      // => B-frag ds_read_b128 start-bank = 4*(r+q): perfect 8-cycle tiling

typedef __attribute__((ext_vector_type(8))) short  short8;
typedef __attribute__((ext_vector_type(4))) float  floatx4;
typedef __attribute__((ext_vector_type(4))) unsigned short ushort4v;
typedef __attribute__((ext_vector_type(4))) float  float4v;

__device__ inline unsigned short f2bf(float x) {
    __hip_bfloat16 h = __float2bfloat16(x);
    union { __hip_bfloat16 h; unsigned short u; } c; c.h = h;
    return c.u;
}
__device__ inline unsigned char f2fp8(float x) {
    __hip_fp8_e4m3 t(x);
    return (unsigned char)t.__x;
}
__device__ inline float fp8f(unsigned v) {
    __hip_fp8_e4m3 t; t.__x = (unsigned char)v;
    return (float)t;
}

// ---------------- Stage 0: features f32 -> fp8 e4m3 table (25.6 MB) ----------------
__global__ __launch_bounds__(256) void fconv8_kernel(
    const float* __restrict__ F, unsigned char* __restrict__ F8)
{
    const size_t i = ((size_t)blockIdx.x * 256 + threadIdx.x) * 8;
    float4v a = *(const float4v*)(F + i);
    float4v b = *(const float4v*)(F + i + 4);
    union { unsigned char c[8]; uint2 v; } o;
    o.c[0] = f2fp8(a[0]); o.c[1] = f2fp8(a[1]); o.c[2] = f2fp8(a[2]); o.c[3] = f2fp8(a[3]);
    o.c[4] = f2fp8(b[0]); o.c[5] = f2fp8(b[1]); o.c[6] = f2fp8(b[2]); o.c[7] = f2fp8(b[3]);
    *(uint2*)(F8 + i) = o.v;
}

// ---------------- Stage 0b: W f32 -> bf16 ----------------
__global__ __launch_bounds__(256) void wconv_kernel(
    const float* __restrict__ W, unsigned short* __restrict__ Wb)
{
    const int i = blockIdx.x * 256 + threadIdx.x;   // grid sized exactly 256*512
    Wb[i] = f2bf(W[i]);
}

// ---------------- Fused: gather+mean -> LDS tile -> MFMA GEMM -> ReLU -> out ----------
// Block: 256 threads (4 waves), NTILE=48 batch items.
// Phase 1: wave stages 12 items: self row from f32 F (16B/lane), 25 neighbor rows
//          from fp8 F8 (4B/lane), f32 accumulate, bf16 into LDS [48][520].
// Phase 2: out[e,b] = relu(sum_k W[e,k]*C[b,k]); M=256 (wave covers 64 rows),
//          N=48 (3 x 16-col tiles), K=512. A from global (L2-resident W), B from LDS.
// MFMA 16x16x32 bf16 layouts (guide-verified):
//   A: lane holds A[m=lane&15][k=(lane>>4)*8+j]; B: B[k=(lane>>4)*8+j][n=lane&15]
//   D: row=(lane>>4)*4+reg, col=lane&15
__global__ __launch_bounds__(256, 3) void enc_kernel(
    const float* __restrict__ F,            // [N_NODES, 256] f32
    const unsigned char* __restrict__ F8,   // [N_NODES, 256] fp8
    const unsigned short* __restrict__ Wb,  // [256, 512] bf16
    const int* __restrict__ nodes,
    const int* __restrict__ neigh,          // [BATCH, NSAMP]
    float* __restrict__ out)                // [256, BATCH] f32
{
    __shared__ unsigned short cl[NTILE * LSTRIDE];  // 49,920 B -> 3 blocks/CU

    const int lane = threadIdx.x & 63;
    const int wave = threadIdx.x >> 6;
    const int q = lane >> 4;
    const int r = lane & 15;
    const int nbase = blockIdx.x * NTILE;

    // ---- Phase 1: gather + mean into LDS ----
    for (int it = 0; it < NTILE / 4; ++it) {
        const int li = wave * (NTILE / 4) + it;     // LDS row 0..47
        int b = nbase + li;
        if (b >= BATCH) b = BATCH - 1;              // duplicate work, stores guarded

        const int node = nodes[b];                  // wave-uniform
        float4v sv = *(const float4v*)(F + (size_t)node * FEAT + lane * 4);

        const int* nb = neigh + (size_t)b * NSAMP;
        float s0 = 0.f, s1 = 0.f, s2 = 0.f, s3 = 0.f;
        #pragma unroll
        for (int j = 0; j < NSAMP; ++j) {
            const int idx = nb[j];                  // wave-uniform -> scalar load
            unsigned wv = *(const unsigned*)(F8 + (size_t)idx * FEAT + lane * 4);
            s0 += fp8f(wv);
            s1 += fp8f(wv >> 8);
            s2 += fp8f(wv >> 16);
            s3 += fp8f(wv >> 24);
        }
        const float inv = 1.0f / NSAMP;
        float m0 = s0 * inv, m1 = s1 * inv, m2 = s2 * inv, m3 = s3 * inv;
        if (m0 != m0) m0 = NAN_FILL;
        if (m1 != m1) m1 = NAN_FILL;
        if (m2 != m2) m2 = NAN_FILL;
        if (m3 != m3) m3 = NAN_FILL;

        unsigned short* row = cl + li * LSTRIDE;
        ushort4v s; s[0] = f2bf(sv[0]); s[1] = f2bf(sv[1]); s[2] = f2bf(sv[2]); s[3] = f2bf(sv[3]);
        *(ushort4v*)(row + lane * 4) = s;
        ushort4v m; m[0] = f2bf(m0); m[1] = f2bf(m1); m[2] = f2bf(m2); m[3] = f2bf(m3);
        *(ushort4v*)(row + FEAT + lane * 4) = m;
    }
    __syncthreads();

    // ---- Phase 2: MFMA GEMM from LDS tile ----
    const int mbase = wave * 64;
    const short* Wp = (const short*)Wb;
    const short* cp = (const short*)cl;

    floatx4 acc[4][3] = {};

    for (int k = 0; k < KDIM; k += 32) {
        short8 afr[4], bfr[3];
        #pragma unroll
        for (int mt = 0; mt < 4; ++mt) {
            const short* p = Wp + (size_t)(mbase + mt * 16 + r) * KDIM + k + q * 8;
            afr[mt] = *(const short8*)p;
        }
        #pragma unroll
        for (int nt = 0; nt < 3; ++nt) {
            const short* p = cp + (nt * 16 + r) * LSTRIDE + k + q * 8;
            bfr[nt] = *(const short8*)p;
        }
        #pragma unroll
        for (int mt = 0; mt < 4; ++mt)
            #pragma unroll
            for (int nt = 0; nt < 3; ++nt)
                acc[mt][nt] = __builtin_amdgcn_mfma_f32_16x16x32_bf16(
                    afr[mt], bfr[nt], acc[mt][nt], 0, 0, 0);
    }

    // ---- Epilogue: ReLU + store ----
    #pragma unroll
    for (int mt = 0; mt < 4; ++mt) {
        #pragma unroll
        for (int nt = 0; nt < 3; ++nt) {
            const int col = nbase + nt * 16 + r;
            if (col < BATCH) {
                #pragma unroll
                for (int i = 0; i < 4; ++i) {
                    const int row = mbase + mt * 16 + q * 4 + i;
                    float v = acc[mt][nt][i];
                    out[(size_t)row * BATCH + col] = v > 0.f ? v : 0.f;
                }
            }
        }
    }
}

extern "C" void kernel_launch(void* const* d_in, const int* in_sizes, int n_in,
                              void* d_out, int out_size, void* d_ws, size_t ws_size,
                              hipStream_t stream) {
    const float* features = (const float*)d_in[0];   // [100000, 256] f32
    const float* weight   = (const float*)d_in[1];   // [256, 512] f32
    const int*   nodes    = (const int*)d_in[2];     // [50000]
    const int*   neigh    = (const int*)d_in[3];     // [50000, 25]
    float* out = (float*)d_out;                      // [256, 50000] f32

    unsigned char* F8  = (unsigned char*)d_ws;                         // 25.6 MB
    unsigned short* Wb = (unsigned short*)(F8 + (size_t)N_NODES * FEAT); // +0.25 MB

    fconv8_kernel<<<(N_NODES * FEAT) / (256 * 8), 256, 0, stream>>>(features, F8);
    wconv_kernel<<<(EMBED * KDIM) / 256, 256, 0, stream>>>(weight, Wb);

    const int nblocks = (BATCH + NTILE - 1) / NTILE;  // 1042
    enc_kernel<<<nblocks, 256, 0, stream>>>(features, F8, Wb, nodes, neigh, out);
}